// Round 11
// baseline (56.548 us; speedup 1.0000x reference)
//
#include <hip/hip_runtime.h>
#include <math.h>

#define NN 2048
#define CC 128
#define EPSF 1e-16f

typedef __attribute__((ext_vector_type(8))) short bf16x8;
typedef __attribute__((ext_vector_type(4))) float f32x4;

__device__ __forceinline__ float softplusf(float x) {
  return fmaxf(x, 0.0f) + log1pf(__expf(-fabsf(x)));
}

union U8 { uint u[4]; bf16x8 v; };

// split 8 fp32 into bf16 hi (truncate) + bf16 lo (residual, truncate),
// packed for MFMA; also accumulate sum of squares of the originals.
__device__ __forceinline__ void split8(float4 a, float4 b, bf16x8& hi,
                                       bf16x8& lo, float& sq) {
  float f[8] = {a.x, a.y, a.z, a.w, b.x, b.y, b.z, b.w};
  U8 H, L;
#pragma unroll
  for (int i = 0; i < 4; ++i) {
    float f0 = f[2 * i], f1 = f[2 * i + 1];
    sq += f0 * f0;
    sq += f1 * f1;
    uint u0 = __float_as_uint(f0), u1 = __float_as_uint(f1);
    uint m0 = u0 & 0xffff0000u, m1 = u1 & 0xffff0000u;
    float r0 = f0 - __uint_as_float(m0);
    float r1 = f1 - __uint_as_float(m1);
    H.u[i] = (u0 >> 16) | m1;
    L.u[i] = (__float_as_uint(r0) >> 16) | (__float_as_uint(r1) & 0xffff0000u);
  }
  hi = H.v;
  lo = L.v;
}

// ---------------- prep: split M and k into frag-ordered bf16 hi/lo, ----
// ---------------- row norms, and per-row activation scalars ------------
__global__ __launch_bounds__(256) void ntm_prep_kernel(
    const float* __restrict__ kptr, const float* __restrict__ beta_,
    const float* __restrict__ g_, const float* __restrict__ s_,
    const float* __restrict__ gamma_, const float* __restrict__ M,
    bf16x8* __restrict__ Mhf, bf16x8* __restrict__ Mlf,
    bf16x8* __restrict__ Khf, bf16x8* __restrict__ Klf,
    float* __restrict__ imn, float* __restrict__ zb, float* __restrict__ gvv,
    float* __restrict__ gmv, float* __restrict__ s0a, float* __restrict__ s1a,
    float* __restrict__ s2a) {
  const int bid = blockIdx.x;
  const int t = threadIdx.x;
  if (bid < 96) {
    const int lane = t & 63;
    const int wv = t >> 6;
    const int l15 = lane & 15;
    const int lg = lane >> 4;
    const bool isM = bid < 32;
    const int grp = (isM ? bid : bid - 32) * 4 + wv;  // M: 0..127, K: 0..255
    const float* src = (isM ? M : kptr) + (grp * 16 + l15) * CC + lg * 8;
    bf16x8* dh = (isM ? Mhf : Khf) + (grp * 4) * 64 + lane;
    bf16x8* dl = (isM ? Mlf : Klf) + (grp * 4) * 64 + lane;
    float sq = 0.f;
#pragma unroll
    for (int ks = 0; ks < 4; ++ks) {
      float4 a0 = *(const float4*)(src + ks * 32);
      float4 a1 = *(const float4*)(src + ks * 32 + 4);
      bf16x8 h, l;
      split8(a0, a1, h, l, sq);
      dh[ks * 64] = h;
      dl[ks * 64] = l;
    }
    sq += __shfl_xor(sq, 16, 64);
    sq += __shfl_xor(sq, 32, 64);
    if (lg == 0) {
      const int row = grp * 16 + l15;
      if (isM) {
        imn[row] = 1.0f / sqrtf(sq);
      } else {
        zb[row] = softplusf(beta_[row]) / sqrtf(sq);  // beta * (1/||k||)
      }
    }
  } else {
    const int r = (bid - 96) * 256 + t;  // 0..4095
    gvv[r] = 1.0f / (1.0f + __expf(-g_[r]));
    gmv[r] = 1.0f + softplusf(gamma_[r]);
    float sh0 = s_[3 * r], sh1 = s_[3 * r + 1], sh2 = s_[3 * r + 2];
    float shm = fmaxf(sh0, fmaxf(sh1, sh2));
    float e0 = __expf(sh0 - shm), e1 = __expf(sh1 - shm), e2 = __expf(sh2 - shm);
    float sden = 1.0f / (e0 + e1 + e2);
    s0a[r] = e0 * sden;
    s1a[r] = e1 * sden;
    s2a[r] = e2 * sden;
  }
}

// ---------------- main: MFMA matmul + fused softmax/gate/conv/sharpen ----
// 512 blocks = 2 blocks/CU. Block pair kg=bg>>1 shares a 16-row group:
// phase 1 (MFMA) computed identically by both; phase 2 split by q:
// half=bg&1 handles q in {2*half, 2*half+1} (rows lg*4+q). Inter-block
// phase overlap fills the CU while one block sits in barrier-synced VALU.
__global__ __launch_bounds__(1024) void ntm_main_kernel(
    const float* __restrict__ w_prev, const bf16x8* __restrict__ Mhf,
    const bf16x8* __restrict__ Mlf, const bf16x8* __restrict__ Khf,
    const bf16x8* __restrict__ Klf, const float* __restrict__ imn,
    const float* __restrict__ zb, const float* __restrict__ gvv,
    const float* __restrict__ gmv, const float* __restrict__ s0a,
    const float* __restrict__ s1a, const float* __restrict__ s2a,
    float* __restrict__ out) {
  __shared__ float red[16][16];       // [row][wave] partial sums
  __shared__ float edges[16][16][2];  // [row][wave][first,last] w_g

  const int t = threadIdx.x;
  const int lane = t & 63;
  const int w = __builtin_amdgcn_readfirstlane(t >> 6);  // 0..15
  const int l15 = lane & 15;
  const int lg = lane >> 4;  // 0..3
  const int bg = blockIdx.x;
  const int kg = bg >> 1;          // 16-row group 0..255
  const int half = bg & 1;         // q-half: 0 -> q{0,1}, 1 -> q{2,3}
  const int b0 = kg * 16;

  // ---- A fragments (k rows), precomputed ----
  bf16x8 ah[4], al[4];
#pragma unroll
  for (int ks = 0; ks < 4; ++ks) {
    ah[ks] = Khf[(kg * 4 + ks) * 64 + lane];
    al[ks] = Klf[(kg * 4 + ks) * 64 + lane];
  }

  // ---- MFMA: ks-outer, tt-inner (identical for both halves) ----
  f32x4 accT[8];
#pragma unroll
  for (int tt = 0; tt < 8; ++tt) accT[tt] = (f32x4){0.f, 0.f, 0.f, 0.f};

#pragma unroll
  for (int ks = 0; ks < 4; ++ks) {
    bf16x8 bh[8], bl[8];
#pragma unroll
    for (int tt = 0; tt < 8; ++tt) {
      const int gM = 8 * w + tt;  // M row-group (16 rows each)
      bh[tt] = Mhf[(gM * 4 + ks) * 64 + lane];
      bl[tt] = Mlf[(gM * 4 + ks) * 64 + lane];
    }
#pragma unroll
    for (int tt = 0; tt < 8; ++tt) {
      accT[tt] = __builtin_amdgcn_mfma_f32_16x16x32_bf16(ah[ks], bh[tt], accT[tt], 0, 0, 0);
      accT[tt] = __builtin_amdgcn_mfma_f32_16x16x32_bf16(al[ks], bh[tt], accT[tt], 0, 0, 0);
      accT[tt] = __builtin_amdgcn_mfma_f32_16x16x32_bf16(ah[ks], bl[tt], accT[tt], 0, 0, 0);
    }
  }
  // D layout: col(n) = 128w + 16tt + l15 ; row(batch) = lg*4 + q

  float imn_t[8];
#pragma unroll
  for (int tt = 0; tt < 8; ++tt) imn_t[tt] = imn[128 * w + 16 * tt + l15];

  // prefetch w_prev + scalars for OWNED q only (qi 0,1 <-> q = 2*half+qi)
  float wp[2][8];
  float zbv[2], gvq[2];
#pragma unroll
  for (int qi = 0; qi < 2; ++qi) {
    const int rr = lg * 4 + 2 * half + qi;
    const size_t rbase = (size_t)(b0 + rr) * NN + 128 * w + l15;
#pragma unroll
    for (int tt = 0; tt < 8; ++tt) wp[qi][tt] = w_prev[rbase + 16 * tt];
    zbv[qi] = zb[b0 + rr];
    gvq[qi] = gvv[b0 + rr];
  }

  // ---- phase 2a: logits -> exp -> per-wave row sums (owned q only) ----
#define PH2A(Q, QI)                                                       \
  {                                                                       \
    const int rr = lg * 4 + (Q);                                          \
    float rs = 0.f;                                                       \
    _Pragma("unroll") for (int tt = 0; tt < 8; ++tt) {                    \
      float e = __expf(accT[tt][(Q)] * imn_t[tt] * zbv[(QI)]);            \
      accT[tt][(Q)] = e;                                                  \
      rs += e;                                                            \
    }                                                                     \
    rs += __shfl_xor(rs, 1, 64);                                          \
    rs += __shfl_xor(rs, 2, 64);                                          \
    rs += __shfl_xor(rs, 4, 64);                                          \
    rs += __shfl_xor(rs, 8, 64);                                          \
    if (l15 == 0) red[rr][w] = rs;                                        \
  }
  if (half) { PH2A(2, 0); PH2A(3, 1); } else { PH2A(0, 0); PH2A(1, 1); }
#undef PH2A
  __syncthreads();  // B1

  // ---- phase 2b: softmax-normalize, gate with w_prev, write slab edges ----
#define PH2B(Q, QI)                                                       \
  {                                                                       \
    const int rr = lg * 4 + (Q);                                          \
    float4 p0 = *(const float4*)&red[rr][0];                              \
    float4 p1 = *(const float4*)&red[rr][4];                              \
    float4 p2 = *(const float4*)&red[rr][8];                              \
    float4 p3 = *(const float4*)&red[rr][12];                             \
    float tot = (p0.x + p0.y + p0.z + p0.w) + (p1.x + p1.y + p1.z + p1.w) \
              + (p2.x + p2.y + p2.z + p2.w) + (p3.x + p3.y + p3.z + p3.w);\
    const float gv = gvq[(QI)];                                           \
    const float ge = gv / tot;                                            \
    const float om = 1.0f - gv;                                           \
    _Pragma("unroll") for (int tt = 0; tt < 8; ++tt) {                    \
      accT[tt][(Q)] = ge * accT[tt][(Q)] + om * wp[(QI)][tt];             \
    }                                                                     \
    if (l15 == 0) edges[rr][w][0] = accT[0][(Q)];                         \
    if (l15 == 15) edges[rr][w][1] = accT[7][(Q)];                        \
  }
  if (half) { PH2B(2, 0); PH2B(3, 1); } else { PH2B(0, 0); PH2B(1, 1); }
#undef PH2B
  __syncthreads();  // B2

  // ---- phase 2c: circular conv (in-group shuffles) + sharpen + row sums ----
  const int tm = (lane & 48) | ((lane + 15) & 15);
  const int tp = (lane & 48) | ((lane + 1) & 15);
#define PH2C(Q, QI)                                                       \
  {                                                                       \
    const int rr = lg * 4 + (Q);                                          \
    const float sh0 = s0a[b0 + rr];                                       \
    const float sh1 = s1a[b0 + rr];                                       \
    const float sh2 = s2a[b0 + rr];                                       \
    const float gammav = gmv[b0 + rr];                                    \
    const float eL = edges[rr][(w + 15) & 15][1];                         \
    const float eR = edges[rr][(w + 1) & 15][0];                          \
    float sm[8], sp[8];                                                   \
    _Pragma("unroll") for (int tt = 0; tt < 8; ++tt) {                    \
      sm[tt] = __shfl(accT[tt][(Q)], tm, 64);                             \
      sp[tt] = __shfl(accT[tt][(Q)], tp, 64);                             \
    }                                                                     \
    float rs = 0.f;                                                       \
    _Pragma("unroll") for (int tt = 0; tt < 8; ++tt) {                    \
      float pv = (l15 == 0) ? ((tt == 0) ? eL : sm[tt - 1]) : sm[tt];     \
      float nx = (l15 == 15) ? ((tt == 7) ? eR : sp[tt + 1]) : sp[tt];    \
      float wt = sh0 * pv + sh1 * accT[tt][(Q)] + sh2 * nx;               \
      float p = __expf(gammav * __logf(wt));                              \
      accT[tt][(Q)] = p;                                                  \
      rs += p;                                                            \
    }                                                                     \
    rs += __shfl_xor(rs, 1, 64);                                          \
    rs += __shfl_xor(rs, 2, 64);                                          \
    rs += __shfl_xor(rs, 4, 64);                                          \
    rs += __shfl_xor(rs, 8, 64);                                          \
    if (l15 == 0) red[rr][w] = rs;                                        \
  }
  if (half) { PH2C(2, 0); PH2C(3, 1); } else { PH2C(0, 0); PH2C(1, 1); }
#undef PH2C
  __syncthreads();  // B3

  // ---- phase 2d: final normalize + store ----
#define PH2D(Q, QI)                                                       \
  {                                                                       \
    const int rr = lg * 4 + (Q);                                          \
    float4 p0 = *(const float4*)&red[rr][0];                              \
    float4 p1 = *(const float4*)&red[rr][4];                              \
    float4 p2 = *(const float4*)&red[rr][8];                              \
    float4 p3 = *(const float4*)&red[rr][12];                             \
    float tot = (p0.x + p0.y + p0.z + p0.w) + (p1.x + p1.y + p1.z + p1.w) \
              + (p2.x + p2.y + p2.z + p2.w) + (p3.x + p3.y + p3.z + p3.w);\
    const float pinv = 1.0f / (tot + EPSF);                               \
    const size_t rbase = (size_t)(b0 + rr) * NN + 128 * w + l15;          \
    _Pragma("unroll") for (int tt = 0; tt < 8; ++tt) {                    \
      out[rbase + 16 * tt] = accT[tt][(Q)] * pinv;                        \
    }                                                                     \
  }
  if (half) { PH2D(2, 0); PH2D(3, 1); } else { PH2D(0, 0); PH2D(1, 1); }
#undef PH2D
}

// ---------------- fallback (round-4 monolith, no workspace) ----------------
__global__ __launch_bounds__(1024) void ntm_main_fallback(
    const float* __restrict__ kptr, const float* __restrict__ beta_,
    const float* __restrict__ g_, const float* __restrict__ s_,
    const float* __restrict__ gamma_, const float* __restrict__ w_prev,
    const float* __restrict__ Mptr, float* __restrict__ out) {
  __shared__ float red[16][16];
  __shared__ float edges[16][16][2];
  const int t = threadIdx.x;
  const int lane = t & 63;
  const int w = __builtin_amdgcn_readfirstlane(t >> 6);
  const int l15 = lane & 15;
  const int lg = lane >> 4;
  const int b0 = blockIdx.x * 16;

  const float* kr = kptr + (b0 + l15) * CC + lg * 8;
  bf16x8 ah[4], al[4];
  float ksq = 0.f;
#pragma unroll
  for (int ks = 0; ks < 4; ++ks) {
    float4 a0 = *(const float4*)(kr + ks * 32);
    float4 a1 = *(const float4*)(kr + ks * 32 + 4);
    split8(a0, a1, ah[ks], al[ks], ksq);
  }
  ksq += __shfl_xor(ksq, 16, 64);
  ksq += __shfl_xor(ksq, 32, 64);
  const float ikn_own = 1.0f / sqrtf(ksq);

  f32x4 accT[8];
  float imn[8];
#pragma unroll
  for (int tt = 0; tt < 8; ++tt) {
    const int n0t = 128 * w + 16 * tt;
    const float* mr = Mptr + (size_t)(n0t + l15) * CC + lg * 8;
    f32x4 acc = {0.f, 0.f, 0.f, 0.f};
    float msq = 0.f;
#pragma unroll
    for (int ks = 0; ks < 4; ++ks) {
      float4 m0 = *(const float4*)(mr + ks * 32);
      float4 m1 = *(const float4*)(mr + ks * 32 + 4);
      bf16x8 bh, bl;
      split8(m0, m1, bh, bl, msq);
      acc = __builtin_amdgcn_mfma_f32_16x16x32_bf16(ah[ks], bh, acc, 0, 0, 0);
      acc = __builtin_amdgcn_mfma_f32_16x16x32_bf16(al[ks], bh, acc, 0, 0, 0);
      acc = __builtin_amdgcn_mfma_f32_16x16x32_bf16(ah[ks], bl, acc, 0, 0, 0);
    }
    msq += __shfl_xor(msq, 16, 64);
    msq += __shfl_xor(msq, 32, 64);
    imn[tt] = 1.0f / sqrtf(msq);
    accT[tt] = acc;
  }

#pragma unroll
  for (int q = 0; q < 4; ++q) {
    const int rr = lg * 4 + q;
    const float zb = softplusf(beta_[b0 + rr]) * __shfl(ikn_own, rr, 64);
    float rs = 0.f;
#pragma unroll
    for (int tt = 0; tt < 8; ++tt) {
      float e = __expf(accT[tt][q] * imn[tt] * zb);
      accT[tt][q] = e;
      rs += e;
    }
    rs += __shfl_xor(rs, 1, 64);
    rs += __shfl_xor(rs, 2, 64);
    rs += __shfl_xor(rs, 4, 64);
    rs += __shfl_xor(rs, 8, 64);
    if (l15 == 0) red[rr][w] = rs;
  }
  __syncthreads();

#pragma unroll
  for (int q = 0; q < 4; ++q) {
    const int rr = lg * 4 + q;
    float4 p0 = *(const float4*)&red[rr][0];
    float4 p1 = *(const float4*)&red[rr][4];
    float4 p2 = *(const float4*)&red[rr][8];
    float4 p3 = *(const float4*)&red[rr][12];
    float tot = (p0.x + p0.y + p0.z + p0.w) + (p1.x + p1.y + p1.z + p1.w) +
                (p2.x + p2.y + p2.z + p2.w) + (p3.x + p3.y + p3.z + p3.w);
    const float gv = 1.0f / (1.0f + __expf(-g_[b0 + rr]));
    const float ge = gv / tot;
    const float om = 1.0f - gv;
    const size_t rbase = (size_t)(b0 + rr) * NN + 128 * w + l15;
#pragma unroll
    for (int tt = 0; tt < 8; ++tt) {
      float wpv = w_prev[rbase + 16 * tt];
      accT[tt][q] = ge * accT[tt][q] + om * wpv;
    }
    if (l15 == 0) edges[rr][w][0] = accT[0][q];
    if (l15 == 15) edges[rr][w][1] = accT[7][q];
  }
  __syncthreads();

  const int tm = (lane & 48) | ((lane + 15) & 15);
  const int tp = (lane & 48) | ((lane + 1) & 15);
#pragma unroll
  for (int q = 0; q < 4; ++q) {
    const int rr = lg * 4 + q;
    float sh0 = s_[3 * (b0 + rr)];
    float sh1 = s_[3 * (b0 + rr) + 1];
    float sh2 = s_[3 * (b0 + rr) + 2];
    float shm = fmaxf(sh0, fmaxf(sh1, sh2));
    float e0 = __expf(sh0 - shm), e1 = __expf(sh1 - shm), e2 = __expf(sh2 - shm);
    float sden = 1.0f / (e0 + e1 + e2);
    sh0 = e0 * sden; sh1 = e1 * sden; sh2 = e2 * sden;
    const float gammav = 1.0f + softplusf(gamma_[b0 + rr]);
    const float eL = edges[rr][(w + 15) & 15][1];
    const float eR = edges[rr][(w + 1) & 15][0];
    float sm[8], sp[8];
#pragma unroll
    for (int tt = 0; tt < 8; ++tt) {
      sm[tt] = __shfl(accT[tt][q], tm, 64);
      sp[tt] = __shfl(accT[tt][q], tp, 64);
    }
    float rs = 0.f;
#pragma unroll
    for (int tt = 0; tt < 8; ++tt) {
      float pv = (l15 == 0) ? ((tt == 0) ? eL : sm[tt - 1]) : sm[tt];
      float nx = (l15 == 15) ? ((tt == 7) ? eR : sp[tt + 1]) : sp[tt];
      float wt = sh0 * pv + sh1 * accT[tt][q] + sh2 * nx;
      float p = __expf(gammav * __logf(wt));
      accT[tt][q] = p;
      rs += p;
    }
    rs += __shfl_xor(rs, 1, 64);
    rs += __shfl_xor(rs, 2, 64);
    rs += __shfl_xor(rs, 4, 64);
    rs += __shfl_xor(rs, 8, 64);
    if (l15 == 0) red[rr][w] = rs;
  }
  __syncthreads();

#pragma unroll
  for (int q = 0; q < 4; ++q) {
    const int rr = lg * 4 + q;
    float4 p0 = *(const float4*)&red[rr][0];
    float4 p1 = *(const float4*)&red[rr][4];
    float4 p2 = *(const float4*)&red[rr][8];
    float4 p3 = *(const float4*)&red[rr][12];
    float tot = (p0.x + p0.y + p0.z + p0.w) + (p1.x + p1.y + p1.z + p1.w) +
                (p2.x + p2.y + p2.z + p2.w) + (p3.x + p3.y + p3.z + p3.w);
    const float pinv = 1.0f / (tot + EPSF);
    const size_t rbase = (size_t)(b0 + rr) * NN + 128 * w + l15;
#pragma unroll
    for (int tt = 0; tt < 8; ++tt) {
      out[rbase + 16 * tt] = accT[tt][q] * pinv;
    }
  }
}

extern "C" void kernel_launch(void* const* d_in, const int* in_sizes, int n_in,
                              void* d_out, int out_size, void* d_ws, size_t ws_size,
                              hipStream_t stream) {
  const float* k = (const float*)d_in[0];
  const float* beta = (const float*)d_in[1];
  const float* g = (const float*)d_in[2];
  const float* s = (const float*)d_in[3];
  const float* gamma = (const float*)d_in[4];
  const float* w_prev = (const float*)d_in[5];
  const float* M = (const float*)d_in[6];
  float* out = (float*)d_out;

  // workspace layout (bytes)
  char* ws = (char*)d_ws;
  bf16x8* Mhf = (bf16x8*)(ws + 0);        // 512 KB (128 grp * 4 ks * 64 ln)
  bf16x8* Mlf = (bf16x8*)(ws + 524288);   // 512 KB
  bf16x8* Khf = (bf16x8*)(ws + 1048576);  // 1 MB (256 grp)
  bf16x8* Klf = (bf16x8*)(ws + 2097152);  // 1 MB
  float* imn = (float*)(ws + 3145728);    // 2048
  float* zb = imn + 2048;                 // 4096
  float* gvv = zb + 4096;
  float* gmv = gvv + 4096;
  float* s0a = gmv + 4096;
  float* s1a = s0a + 4096;
  float* s2a = s1a + 4096;
  const size_t need = 3145728 + 2048 * 4 + 6 * 4096 * 4;

  if (ws_size >= need) {
    ntm_prep_kernel<<<112, 256, 0, stream>>>(k, beta, g, s, gamma, M, Mhf, Mlf,
                                             Khf, Klf, imn, zb, gvv, gmv, s0a,
                                             s1a, s2a);
    ntm_main_kernel<<<512, 1024, 0, stream>>>(w_prev, Mhf, Mlf, Khf, Klf, imn,
                                              zb, gvv, gmv, s0a, s1a, s2a, out);
  } else {
    ntm_main_fallback<<<256, 1024, 0, stream>>>(k, beta, g, s, gamma, w_prev,
                                                M, out);
  }
}

// Round 12
// 45.387 us; speedup vs baseline: 1.2459x; 1.2459x over previous
//
#include <hip/hip_runtime.h>
#include <math.h>

#define NN 2048
#define CC 128
#define EPSF 1e-16f

typedef __attribute__((ext_vector_type(8))) short bf16x8;
typedef __attribute__((ext_vector_type(4))) float f32x4;

__device__ __forceinline__ float softplusf(float x) {
  return fmaxf(x, 0.0f) + log1pf(__expf(-fabsf(x)));
}

union U8 { uint u[4]; bf16x8 v; };

// split 8 fp32 into bf16 hi (truncate) + bf16 lo (residual, truncate),
// packed for MFMA; also accumulate sum of squares of the originals.
__device__ __forceinline__ void split8(float4 a, float4 b, bf16x8& hi,
                                       bf16x8& lo, float& sq) {
  float f[8] = {a.x, a.y, a.z, a.w, b.x, b.y, b.z, b.w};
  U8 H, L;
#pragma unroll
  for (int i = 0; i < 4; ++i) {
    float f0 = f[2 * i], f1 = f[2 * i + 1];
    sq += f0 * f0;
    sq += f1 * f1;
    uint u0 = __float_as_uint(f0), u1 = __float_as_uint(f1);
    uint m0 = u0 & 0xffff0000u, m1 = u1 & 0xffff0000u;
    float r0 = f0 - __uint_as_float(m0);
    float r1 = f1 - __uint_as_float(m1);
    H.u[i] = (u0 >> 16) | m1;
    L.u[i] = (__float_as_uint(r0) >> 16) | (__float_as_uint(r1) & 0xffff0000u);
  }
  hi = H.v;
  lo = L.v;
}

// ---------------- prep: split M and k into frag-ordered bf16 hi/lo ------
// M rows are PERMUTED into fragment slots so that in the main kernel,
// tile tt of wave w, slot l15 holds M row n = 128w + 8*l15 + tt. Then each
// lane's 8 accumulators (tt=0..7) cover 8 CONSECUTIVE n -> float4 global
// accesses in phase 2 and in-register conv neighbors.
// Group g (0..127), slot l15: n = (g>>3)*128 + 8*l15 + (g&7).
__global__ __launch_bounds__(256) void ntm_prep_kernel(
    const float* __restrict__ kptr, const float* __restrict__ beta_,
    const float* __restrict__ g_, const float* __restrict__ s_,
    const float* __restrict__ gamma_, const float* __restrict__ M,
    bf16x8* __restrict__ Mhf, bf16x8* __restrict__ Mlf,
    bf16x8* __restrict__ Khf, bf16x8* __restrict__ Klf,
    float* __restrict__ imn, float* __restrict__ zb, float* __restrict__ gvv,
    float* __restrict__ gmv, float* __restrict__ s0a, float* __restrict__ s1a,
    float* __restrict__ s2a) {
  const int bid = blockIdx.x;
  const int t = threadIdx.x;
  if (bid < 96) {
    const int lane = t & 63;
    const int wv = t >> 6;
    const int l15 = lane & 15;
    const int lg = lane >> 4;
    const bool isM = bid < 32;
    const int grp = (isM ? bid : bid - 32) * 4 + wv;  // M: 0..127, K: 0..255
    const int nrow = isM ? ((grp >> 3) * 128 + 8 * l15 + (grp & 7))
                         : (grp * 16 + l15);
    const float* src = (isM ? M : kptr) + nrow * CC + lg * 8;
    bf16x8* dh = (isM ? Mhf : Khf) + (grp * 4) * 64 + lane;
    bf16x8* dl = (isM ? Mlf : Klf) + (grp * 4) * 64 + lane;
    float sq = 0.f;
#pragma unroll
    for (int ks = 0; ks < 4; ++ks) {
      float4 a0 = *(const float4*)(src + ks * 32);
      float4 a1 = *(const float4*)(src + ks * 32 + 4);
      bf16x8 h, l;
      split8(a0, a1, h, l, sq);
      dh[ks * 64] = h;
      dl[ks * 64] = l;
    }
    sq += __shfl_xor(sq, 16, 64);
    sq += __shfl_xor(sq, 32, 64);
    if (lg == 0) {
      if (isM) {
        imn[nrow] = 1.0f / sqrtf(sq);
      } else {
        zb[nrow] = softplusf(beta_[nrow]) / sqrtf(sq);  // beta * (1/||k||)
      }
    }
  } else {
    const int r = (bid - 96) * 256 + t;  // 0..4095
    gvv[r] = 1.0f / (1.0f + __expf(-g_[r]));
    gmv[r] = 1.0f + softplusf(gamma_[r]);
    float sh0 = s_[3 * r], sh1 = s_[3 * r + 1], sh2 = s_[3 * r + 2];
    float shm = fmaxf(sh0, fmaxf(sh1, sh2));
    float e0 = __expf(sh0 - shm), e1 = __expf(sh1 - shm), e2 = __expf(sh2 - shm);
    float sden = 1.0f / (e0 + e1 + e2);
    s0a[r] = e0 * sden;
    s1a[r] = e1 * sden;
    s2a[r] = e2 * sden;
  }
}

// ---------------- main: MFMA matmul + fused softmax/gate/conv/sharpen ----
// 256 blocks x 1024 thr (1 block/CU). Lane (l15) owns n in
// [128w + 8*l15, +8) via the permuted fragment packing: accT[tt][q] is
// n = 128w + 8*l15 + tt, batch row = b0 + lg*4 + q.
__global__ __launch_bounds__(1024) void ntm_main_kernel(
    const float* __restrict__ w_prev, const bf16x8* __restrict__ Mhf,
    const bf16x8* __restrict__ Mlf, const bf16x8* __restrict__ Khf,
    const bf16x8* __restrict__ Klf, const float* __restrict__ imn,
    const float* __restrict__ zb, const float* __restrict__ gvv,
    const float* __restrict__ gmv, const float* __restrict__ s0a,
    const float* __restrict__ s1a, const float* __restrict__ s2a,
    float* __restrict__ out) {
  __shared__ float red[16][16];       // [row][wave] partial sums
  __shared__ float edges[16][16][2];  // [row][wave][first,last] w_g

  const int t = threadIdx.x;
  const int lane = t & 63;
  const int w = __builtin_amdgcn_readfirstlane(t >> 6);  // 0..15
  const int l15 = lane & 15;
  const int lg = lane >> 4;  // 0..3
  const int bg = blockIdx.x;
  const int b0 = bg * 16;

  // ---- A fragments (k rows), precomputed ----
  bf16x8 ah[4], al[4];
#pragma unroll
  for (int ks = 0; ks < 4; ++ks) {
    ah[ks] = Khf[(bg * 4 + ks) * 64 + lane];
    al[ks] = Klf[(bg * 4 + ks) * 64 + lane];
  }

  // ---- MFMA: ks-outer, tt-inner ----
  f32x4 accT[8];
#pragma unroll
  for (int tt = 0; tt < 8; ++tt) accT[tt] = (f32x4){0.f, 0.f, 0.f, 0.f};

#pragma unroll
  for (int ks = 0; ks < 4; ++ks) {
    bf16x8 bh[8], bl[8];
#pragma unroll
    for (int tt = 0; tt < 8; ++tt) {
      const int gM = 8 * w + tt;  // fragment group
      bh[tt] = Mhf[(gM * 4 + ks) * 64 + lane];
      bl[tt] = Mlf[(gM * 4 + ks) * 64 + lane];
    }
#pragma unroll
    for (int tt = 0; tt < 8; ++tt) {
      accT[tt] = __builtin_amdgcn_mfma_f32_16x16x32_bf16(ah[ks], bh[tt], accT[tt], 0, 0, 0);
      accT[tt] = __builtin_amdgcn_mfma_f32_16x16x32_bf16(al[ks], bh[tt], accT[tt], 0, 0, 0);
      accT[tt] = __builtin_amdgcn_mfma_f32_16x16x32_bf16(ah[ks], bl[tt], accT[tt], 0, 0, 0);
    }
  }

  // ---- consecutive-n loads: imn (2x float4), w_prev (2x float4 per q) ----
  const int ncol0 = 128 * w + 8 * l15;  // first n this lane owns
  const float4 i0 = *(const float4*)&imn[ncol0];
  const float4 i1 = *(const float4*)&imn[ncol0 + 4];
  float imn_t[8] = {i0.x, i0.y, i0.z, i0.w, i1.x, i1.y, i1.z, i1.w};

  const float4* w_prev4 = (const float4*)w_prev;
  float wp[4][8];
  float zbv[4], gvq[4];
#pragma unroll
  for (int q = 0; q < 4; ++q) {
    const int rr = lg * 4 + q;
    const size_t r4 = (size_t)(b0 + rr) * (NN / 4) + (ncol0 >> 2);
    float4 wa = w_prev4[r4];
    float4 wb = w_prev4[r4 + 1];
    wp[q][0] = wa.x; wp[q][1] = wa.y; wp[q][2] = wa.z; wp[q][3] = wa.w;
    wp[q][4] = wb.x; wp[q][5] = wb.y; wp[q][6] = wb.z; wp[q][7] = wb.w;
    zbv[q] = zb[b0 + rr];
    gvq[q] = gvv[b0 + rr];
  }

  // ---- phase 2a: logits -> exp -> per-wave row sums ----
#pragma unroll
  for (int q = 0; q < 4; ++q) {
    const int rr = lg * 4 + q;
    float rs = 0.f;
#pragma unroll
    for (int tt = 0; tt < 8; ++tt) {
      float e = __expf(accT[tt][q] * imn_t[tt] * zbv[q]);  // |logit| <= ~5
      accT[tt][q] = e;
      rs += e;
    }
    rs += __shfl_xor(rs, 1, 64);
    rs += __shfl_xor(rs, 2, 64);
    rs += __shfl_xor(rs, 4, 64);
    rs += __shfl_xor(rs, 8, 64);
    if (l15 == 0) red[rr][w] = rs;
  }
  __syncthreads();  // B1

  // ---- phase 2b: softmax-normalize, gate with w_prev, write slab edges ----
#pragma unroll
  for (int q = 0; q < 4; ++q) {
    const int rr = lg * 4 + q;
    float4 p0 = *(const float4*)&red[rr][0];
    float4 p1 = *(const float4*)&red[rr][4];
    float4 p2 = *(const float4*)&red[rr][8];
    float4 p3 = *(const float4*)&red[rr][12];
    float tot = (p0.x + p0.y + p0.z + p0.w) + (p1.x + p1.y + p1.z + p1.w) +
                (p2.x + p2.y + p2.z + p2.w) + (p3.x + p3.y + p3.z + p3.w);
    const float gv = gvq[q];
    const float ge = gv / tot;
    const float om = 1.0f - gv;
#pragma unroll
    for (int tt = 0; tt < 8; ++tt) {
      accT[tt][q] = ge * accT[tt][q] + om * wp[q][tt];
    }
    // slab first (n=128w): tt=0,l15=0 ; slab last (n=128w+127): tt=7,l15=15
    if (l15 == 0) edges[rr][w][0] = accT[0][q];
    if (l15 == 15) edges[rr][w][1] = accT[7][q];
  }
  __syncthreads();  // B2

  // ---- phase 2c: circular conv (in-register + 2 shuffles/q) + sharpen ----
  const int tm = (lane & 48) | ((lane + 15) & 15);
  const int tp = (lane & 48) | ((lane + 1) & 15);
#pragma unroll
  for (int q = 0; q < 4; ++q) {
    const int rr = lg * 4 + q;
    const float sh0 = s0a[b0 + rr];
    const float sh1 = s1a[b0 + rr];
    const float sh2 = s2a[b0 + rr];
    const float gammav = gmv[b0 + rr];
    const float eL = edges[rr][(w + 15) & 15][1];  // w_g[n-1] at slab start
    const float eR = edges[rr][(w + 1) & 15][0];   // w_g[n+1] at slab end

    float wg[8];
#pragma unroll
    for (int tt = 0; tt < 8; ++tt) wg[tt] = accT[tt][q];
    const float pmv = __shfl(wg[7], tm, 64);  // lane l15-1's last = n(0)-1
    const float npv = __shfl(wg[0], tp, 64);  // lane l15+1's first = n(7)+1

    float rs = 0.f;
#pragma unroll
    for (int tt = 0; tt < 8; ++tt) {
      float pv = (tt == 0) ? ((l15 == 0) ? eL : pmv) : wg[tt - 1];
      float nx = (tt == 7) ? ((l15 == 15) ? eR : npv) : wg[tt + 1];
      float wt = sh0 * pv + sh1 * wg[tt] + sh2 * nx;
      float p = __expf(gammav * __logf(wt));  // wt^gamma ; wt>0
      accT[tt][q] = p;
      rs += p;
    }
    rs += __shfl_xor(rs, 1, 64);
    rs += __shfl_xor(rs, 2, 64);
    rs += __shfl_xor(rs, 4, 64);
    rs += __shfl_xor(rs, 8, 64);
    if (l15 == 0) red[rr][w] = rs;
  }
  __syncthreads();  // B3

  // ---- phase 2d: final normalize + float4 stores ----
  float4* out4 = (float4*)out;
#pragma unroll
  for (int q = 0; q < 4; ++q) {
    const int rr = lg * 4 + q;
    float4 p0 = *(const float4*)&red[rr][0];
    float4 p1 = *(const float4*)&red[rr][4];
    float4 p2 = *(const float4*)&red[rr][8];
    float4 p3 = *(const float4*)&red[rr][12];
    float tot = (p0.x + p0.y + p0.z + p0.w) + (p1.x + p1.y + p1.z + p1.w) +
                (p2.x + p2.y + p2.z + p2.w) + (p3.x + p3.y + p3.z + p3.w);
    const float pinv = 1.0f / (tot + EPSF);
    const size_t r4 = (size_t)(b0 + rr) * (NN / 4) + (ncol0 >> 2);
    float4 o0, o1;
    o0.x = accT[0][q] * pinv; o0.y = accT[1][q] * pinv;
    o0.z = accT[2][q] * pinv; o0.w = accT[3][q] * pinv;
    o1.x = accT[4][q] * pinv; o1.y = accT[5][q] * pinv;
    o1.z = accT[6][q] * pinv; o1.w = accT[7][q] * pinv;
    out4[r4] = o0;
    out4[r4 + 1] = o1;
  }
}

// ---------------- fallback (round-4 monolith, no workspace) ----------------
__global__ __launch_bounds__(1024) void ntm_main_fallback(
    const float* __restrict__ kptr, const float* __restrict__ beta_,
    const float* __restrict__ g_, const float* __restrict__ s_,
    const float* __restrict__ gamma_, const float* __restrict__ w_prev,
    const float* __restrict__ Mptr, float* __restrict__ out) {
  __shared__ float red[16][16];
  __shared__ float edges[16][16][2];
  const int t = threadIdx.x;
  const int lane = t & 63;
  const int w = __builtin_amdgcn_readfirstlane(t >> 6);
  const int l15 = lane & 15;
  const int lg = lane >> 4;
  const int b0 = blockIdx.x * 16;

  const float* kr = kptr + (b0 + l15) * CC + lg * 8;
  bf16x8 ah[4], al[4];
  float ksq = 0.f;
#pragma unroll
  for (int ks = 0; ks < 4; ++ks) {
    float4 a0 = *(const float4*)(kr + ks * 32);
    float4 a1 = *(const float4*)(kr + ks * 32 + 4);
    split8(a0, a1, ah[ks], al[ks], ksq);
  }
  ksq += __shfl_xor(ksq, 16, 64);
  ksq += __shfl_xor(ksq, 32, 64);
  const float ikn_own = 1.0f / sqrtf(ksq);

  f32x4 accT[8];
  float imn[8];
#pragma unroll
  for (int tt = 0; tt < 8; ++tt) {
    const int n0t = 128 * w + 16 * tt;
    const float* mr = Mptr + (size_t)(n0t + l15) * CC + lg * 8;
    f32x4 acc = {0.f, 0.f, 0.f, 0.f};
    float msq = 0.f;
#pragma unroll
    for (int ks = 0; ks < 4; ++ks) {
      float4 m0 = *(const float4*)(mr + ks * 32);
      float4 m1 = *(const float4*)(mr + ks * 32 + 4);
      bf16x8 bh, bl;
      split8(m0, m1, bh, bl, msq);
      acc = __builtin_amdgcn_mfma_f32_16x16x32_bf16(ah[ks], bh, acc, 0, 0, 0);
      acc = __builtin_amdgcn_mfma_f32_16x16x32_bf16(al[ks], bh, acc, 0, 0, 0);
      acc = __builtin_amdgcn_mfma_f32_16x16x32_bf16(ah[ks], bl, acc, 0, 0, 0);
    }
    msq += __shfl_xor(msq, 16, 64);
    msq += __shfl_xor(msq, 32, 64);
    imn[tt] = 1.0f / sqrtf(msq);
    accT[tt] = acc;
  }

#pragma unroll
  for (int q = 0; q < 4; ++q) {
    const int rr = lg * 4 + q;
    const float zb = softplusf(beta_[b0 + rr]) * __shfl(ikn_own, rr, 64);
    float rs = 0.f;
#pragma unroll
    for (int tt = 0; tt < 8; ++tt) {
      float e = __expf(accT[tt][q] * imn[tt] * zb);
      accT[tt][q] = e;
      rs += e;
    }
    rs += __shfl_xor(rs, 1, 64);
    rs += __shfl_xor(rs, 2, 64);
    rs += __shfl_xor(rs, 4, 64);
    rs += __shfl_xor(rs, 8, 64);
    if (l15 == 0) red[rr][w] = rs;
  }
  __syncthreads();

#pragma unroll
  for (int q = 0; q < 4; ++q) {
    const int rr = lg * 4 + q;
    float4 p0 = *(const float4*)&red[rr][0];
    float4 p1 = *(const float4*)&red[rr][4];
    float4 p2 = *(const float4*)&red[rr][8];
    float4 p3 = *(const float4*)&red[rr][12];
    float tot = (p0.x + p0.y + p0.z + p0.w) + (p1.x + p1.y + p1.z + p1.w) +
                (p2.x + p2.y + p2.z + p2.w) + (p3.x + p3.y + p3.z + p3.w);
    const float gv = 1.0f / (1.0f + __expf(-g_[b0 + rr]));
    const float ge = gv / tot;
    const float om = 1.0f - gv;
    const size_t rbase = (size_t)(b0 + rr) * NN + 128 * w + l15;
#pragma unroll
    for (int tt = 0; tt < 8; ++tt) {
      float wpv = w_prev[rbase + 16 * tt];
      accT[tt][q] = ge * accT[tt][q] + om * wpv;
    }
    if (l15 == 0) edges[rr][w][0] = accT[0][q];
    if (l15 == 15) edges[rr][w][1] = accT[7][q];
  }
  __syncthreads();

  const int tm = (lane & 48) | ((lane + 15) & 15);
  const int tp = (lane & 48) | ((lane + 1) & 15);
#pragma unroll
  for (int q = 0; q < 4; ++q) {
    const int rr = lg * 4 + q;
    float sh0 = s_[3 * (b0 + rr)];
    float sh1 = s_[3 * (b0 + rr) + 1];
    float sh2 = s_[3 * (b0 + rr) + 2];
    float shm = fmaxf(sh0, fmaxf(sh1, sh2));
    float e0 = __expf(sh0 - shm), e1 = __expf(sh1 - shm), e2 = __expf(sh2 - shm);
    float sden = 1.0f / (e0 + e1 + e2);
    sh0 = e0 * sden; sh1 = e1 * sden; sh2 = e2 * sden;
    const float gammav = 1.0f + softplusf(gamma_[b0 + rr]);
    const float eL = edges[rr][(w + 15) & 15][1];
    const float eR = edges[rr][(w + 1) & 15][0];
    float sm[8], sp[8];
#pragma unroll
    for (int tt = 0; tt < 8; ++tt) {
      sm[tt] = __shfl(accT[tt][q], tm, 64);
      sp[tt] = __shfl(accT[tt][q], tp, 64);
    }
    float rs = 0.f;
#pragma unroll
    for (int tt = 0; tt < 8; ++tt) {
      float pv = (l15 == 0) ? ((tt == 0) ? eL : sm[tt - 1]) : sm[tt];
      float nx = (l15 == 15) ? ((tt == 7) ? eR : sp[tt + 1]) : sp[tt];
      float wt = sh0 * pv + sh1 * accT[tt][q] + sh2 * nx;
      float p = __expf(gammav * __logf(wt));
      accT[tt][q] = p;
      rs += p;
    }
    rs += __shfl_xor(rs, 1, 64);
    rs += __shfl_xor(rs, 2, 64);
    rs += __shfl_xor(rs, 4, 64);
    rs += __shfl_xor(rs, 8, 64);
    if (l15 == 0) red[rr][w] = rs;
  }
  __syncthreads();

#pragma unroll
  for (int q = 0; q < 4; ++q) {
    const int rr = lg * 4 + q;
    float4 p0 = *(const float4*)&red[rr][0];
    float4 p1 = *(const float4*)&red[rr][4];
    float4 p2 = *(const float4*)&red[rr][8];
    float4 p3 = *(const float4*)&red[rr][12];
    float tot = (p0.x + p0.y + p0.z + p0.w) + (p1.x + p1.y + p1.z + p1.w) +
                (p2.x + p2.y + p2.z + p2.w) + (p3.x + p3.y + p3.z + p3.w);
    const float pinv = 1.0f / (tot + EPSF);
    const size_t rbase = (size_t)(b0 + rr) * NN + 128 * w + l15;
#pragma unroll
    for (int tt = 0; tt < 8; ++tt) {
      out[rbase + 16 * tt] = accT[tt][q] * pinv;
    }
  }
}

extern "C" void kernel_launch(void* const* d_in, const int* in_sizes, int n_in,
                              void* d_out, int out_size, void* d_ws, size_t ws_size,
                              hipStream_t stream) {
  const float* k = (const float*)d_in[0];
  const float* beta = (const float*)d_in[1];
  const float* g = (const float*)d_in[2];
  const float* s = (const float*)d_in[3];
  const float* gamma = (const float*)d_in[4];
  const float* w_prev = (const float*)d_in[5];
  const float* M = (const float*)d_in[6];
  float* out = (float*)d_out;

  // workspace layout (bytes)
  char* ws = (char*)d_ws;
  bf16x8* Mhf = (bf16x8*)(ws + 0);        // 512 KB (128 grp * 4 ks * 64 ln)
  bf16x8* Mlf = (bf16x8*)(ws + 524288);   // 512 KB
  bf16x8* Khf = (bf16x8*)(ws + 1048576);  // 1 MB (256 grp)
  bf16x8* Klf = (bf16x8*)(ws + 2097152);  // 1 MB
  float* imn = (float*)(ws + 3145728);    // 2048
  float* zb = imn + 2048;                 // 4096
  float* gvv = zb + 4096;
  float* gmv = gvv + 4096;
  float* s0a = gmv + 4096;
  float* s1a = s0a + 4096;
  float* s2a = s1a + 4096;
  const size_t need = 3145728 + 2048 * 4 + 6 * 4096 * 4;

  if (ws_size >= need) {
    ntm_prep_kernel<<<112, 256, 0, stream>>>(k, beta, g, s, gamma, M, Mhf, Mlf,
                                             Khf, Klf, imn, zb, gvv, gmv, s0a,
                                             s1a, s2a);
    ntm_main_kernel<<<256, 1024, 0, stream>>>(w_prev, Mhf, Mlf, Khf, Klf, imn,
                                              zb, gvv, gmv, s0a, s1a, s2a, out);
  } else {
    ntm_main_fallback<<<256, 1024, 0, stream>>>(k, beta, g, s, gamma, w_prev,
                                                M, out);
  }
}

// Round 13
// 38.478 us; speedup vs baseline: 1.4696x; 1.1796x over previous
//
#include <hip/hip_runtime.h>
#include <math.h>

#define NN 2048
#define CC 128
#define EPSF 1e-16f

typedef __attribute__((ext_vector_type(8))) short bf16x8;
typedef __attribute__((ext_vector_type(4))) float f32x4;

__device__ __forceinline__ float softplusf(float x) {
  return fmaxf(x, 0.0f) + log1pf(__expf(-fabsf(x)));
}
__device__ __forceinline__ float wave_sum(float v) {
#pragma unroll
  for (int o = 32; o; o >>= 1) v += __shfl_xor(v, o, 64);
  return v;
}

union U8 { uint u[4]; bf16x8 v; };

// split 8 fp32 into bf16 hi (truncate) + bf16 lo (residual, truncate),
// packed for MFMA; also accumulate sum of squares of the originals.
__device__ __forceinline__ void split8(float4 a, float4 b, bf16x8& hi,
                                       bf16x8& lo, float& sq) {
  float f[8] = {a.x, a.y, a.z, a.w, b.x, b.y, b.z, b.w};
  U8 H, L;
#pragma unroll
  for (int i = 0; i < 4; ++i) {
    float f0 = f[2 * i], f1 = f[2 * i + 1];
    sq += f0 * f0;
    sq += f1 * f1;
    uint u0 = __float_as_uint(f0), u1 = __float_as_uint(f1);
    uint m0 = u0 & 0xffff0000u, m1 = u1 & 0xffff0000u;
    float r0 = f0 - __uint_as_float(m0);
    float r1 = f1 - __uint_as_float(m1);
    H.u[i] = (u0 >> 16) | m1;
    L.u[i] = (__float_as_uint(r0) >> 16) | (__float_as_uint(r1) & 0xffff0000u);
  }
  hi = H.v;
  lo = L.v;
}

// ---------------- prep: split M and k into frag-ordered bf16 hi/lo ------
// M rows PERMUTED into fragment slots: tile tt of wave w, slot l15 holds
// M row n = 128w + 8*l15 + tt  (group g: n = (g>>3)*128 + 8*l15 + (g&7)).
__global__ __launch_bounds__(256) void ntm_prep_kernel(
    const float* __restrict__ kptr, const float* __restrict__ beta_,
    const float* __restrict__ g_, const float* __restrict__ s_,
    const float* __restrict__ gamma_, const float* __restrict__ M,
    bf16x8* __restrict__ Mhf, bf16x8* __restrict__ Mlf,
    bf16x8* __restrict__ Khf, bf16x8* __restrict__ Klf,
    float* __restrict__ imn, float* __restrict__ zb, float* __restrict__ gvv,
    float* __restrict__ gmv, float* __restrict__ s0a, float* __restrict__ s1a,
    float* __restrict__ s2a) {
  const int bid = blockIdx.x;
  const int t = threadIdx.x;
  if (bid < 96) {
    const int lane = t & 63;
    const int wv = t >> 6;
    const int l15 = lane & 15;
    const int lg = lane >> 4;
    const bool isM = bid < 32;
    const int grp = (isM ? bid : bid - 32) * 4 + wv;  // M: 0..127, K: 0..255
    const int nrow = isM ? ((grp >> 3) * 128 + 8 * l15 + (grp & 7))
                         : (grp * 16 + l15);
    const float* src = (isM ? M : kptr) + nrow * CC + lg * 8;
    bf16x8* dh = (isM ? Mhf : Khf) + (grp * 4) * 64 + lane;
    bf16x8* dl = (isM ? Mlf : Klf) + (grp * 4) * 64 + lane;
    float sq = 0.f;
#pragma unroll
    for (int ks = 0; ks < 4; ++ks) {
      float4 a0 = *(const float4*)(src + ks * 32);
      float4 a1 = *(const float4*)(src + ks * 32 + 4);
      bf16x8 h, l;
      split8(a0, a1, h, l, sq);
      dh[ks * 64] = h;
      dl[ks * 64] = l;
    }
    sq += __shfl_xor(sq, 16, 64);
    sq += __shfl_xor(sq, 32, 64);
    if (lg == 0) {
      if (isM) {
        imn[nrow] = 1.0f / sqrtf(sq);
      } else {
        zb[nrow] = softplusf(beta_[nrow]) / sqrtf(sq);  // beta * (1/||k||)
      }
    }
  } else {
    const int r = (bid - 96) * 256 + t;  // 0..4095
    gvv[r] = 1.0f / (1.0f + __expf(-g_[r]));
    gmv[r] = 1.0f + softplusf(gamma_[r]);
    float sh0 = s_[3 * r], sh1 = s_[3 * r + 1], sh2 = s_[3 * r + 2];
    float shm = fmaxf(sh0, fmaxf(sh1, sh2));
    float e0 = __expf(sh0 - shm), e1 = __expf(sh1 - shm), e2 = __expf(sh2 - shm);
    float sden = 1.0f / (e0 + e1 + e2);
    s0a[r] = e0 * sden;
    s1a[r] = e1 * sden;
    s2a[r] = e2 * sden;
  }
}

// ---------------- main: MFMA+exp, LDS row handoff, wave-per-row stream ----
// 256 blocks x 1024 thr. Phase 1: as R12 (permuted packing, lane owns
// n = 128w+8*l15+tt for row lg*4+q). Handoff: 4 q-chunks through 32KB LDS;
// wave wv then owns complete row b0+wv. Phase 2: barrier-free streaming
// (wave-local softmax denom, in-register conv, float4 w_prev/out).
__global__ __launch_bounds__(1024) void ntm_main_kernel(
    const float* __restrict__ w_prev, const bf16x8* __restrict__ Mhf,
    const bf16x8* __restrict__ Mlf, const bf16x8* __restrict__ Khf,
    const bf16x8* __restrict__ Klf, const float* __restrict__ imn,
    const float* __restrict__ zb, const float* __restrict__ gvv,
    const float* __restrict__ gmv, const float* __restrict__ s0a,
    const float* __restrict__ s1a, const float* __restrict__ s2a,
    float* __restrict__ out) {
  __shared__ float eQ[4][2048];  // 32 KB: rows {lg*4+q} for current chunk q

  const int t = threadIdx.x;
  const int lane = t & 63;
  const int w = __builtin_amdgcn_readfirstlane(t >> 6);  // 0..15
  const int l15 = lane & 15;
  const int lg = lane >> 4;  // 0..3
  const int bg = blockIdx.x;
  const int b0 = bg * 16;

  // ---- A fragments (k rows), precomputed ----
  bf16x8 ah[4], al[4];
#pragma unroll
  for (int ks = 0; ks < 4; ++ks) {
    ah[ks] = Khf[(bg * 4 + ks) * 64 + lane];
    al[ks] = Klf[(bg * 4 + ks) * 64 + lane];
  }

  // ---- MFMA: ks-outer, tt-inner ----
  f32x4 accT[8];
#pragma unroll
  for (int tt = 0; tt < 8; ++tt) accT[tt] = (f32x4){0.f, 0.f, 0.f, 0.f};

#pragma unroll
  for (int ks = 0; ks < 4; ++ks) {
    bf16x8 bh[8], bl[8];
#pragma unroll
    for (int tt = 0; tt < 8; ++tt) {
      const int gM = 8 * w + tt;
      bh[tt] = Mhf[(gM * 4 + ks) * 64 + lane];
      bl[tt] = Mlf[(gM * 4 + ks) * 64 + lane];
    }
#pragma unroll
    for (int tt = 0; tt < 8; ++tt) {
      accT[tt] = __builtin_amdgcn_mfma_f32_16x16x32_bf16(ah[ks], bh[tt], accT[tt], 0, 0, 0);
      accT[tt] = __builtin_amdgcn_mfma_f32_16x16x32_bf16(al[ks], bh[tt], accT[tt], 0, 0, 0);
      accT[tt] = __builtin_amdgcn_mfma_f32_16x16x32_bf16(ah[ks], bl[tt], accT[tt], 0, 0, 0);
    }
  }

  // ---- exp: accT -> e  (lane owns n = ncol0 + tt, row = lg*4 + q) ----
  const int ncol0 = 128 * w + 8 * l15;
  const float4 i0 = *(const float4*)&imn[ncol0];
  const float4 i1 = *(const float4*)&imn[ncol0 + 4];
  float imn_t[8] = {i0.x, i0.y, i0.z, i0.w, i1.x, i1.y, i1.z, i1.w};
#pragma unroll
  for (int q = 0; q < 4; ++q) {
    const float zbv = zb[b0 + lg * 4 + q];
#pragma unroll
    for (int tt = 0; tt < 8; ++tt) {
      accT[tt][q] = __expf(accT[tt][q] * imn_t[tt] * zbv);  // |logit| <= ~5
    }
  }

  // ---- handoff: 4 q-chunks through eQ; wave wv reads row b0+wv ----
  float4 v[8];          // my wave's full row (float4 per 4 consecutive n)
  const int myq = w & 3;
  const int myr4 = w >> 2;
#pragma unroll
  for (int q = 0; q < 4; ++q) {
    *(float4*)&eQ[lg][ncol0] =
        (float4){accT[0][q], accT[1][q], accT[2][q], accT[3][q]};
    *(float4*)&eQ[lg][ncol0 + 4] =
        (float4){accT[4][q], accT[5][q], accT[6][q], accT[7][q]};
    __syncthreads();
    if (myq == q) {
#pragma unroll
      for (int b = 0; b < 8; ++b)
        v[b] = *(const float4*)&eQ[myr4][256 * b + 4 * lane];
    }
    if (q < 3) __syncthreads();  // protect eQ before next chunk's writes
  }

  // ---- phase 2: barrier-free wave-per-row streaming (row = b0 + w) ----
  const int row = b0 + w;
  const int lanem1 = (lane + 63) & 63;
  const int lanep1 = (lane + 1) & 63;

  float lsum = 0.f;
#pragma unroll
  for (int b = 0; b < 8; ++b)
    lsum += (v[b].x + v[b].y) + (v[b].z + v[b].w);
  const float tot = wave_sum(lsum);

  const float gv = gvv[row];
  const float ge = gv / tot;
  const float om = 1.0f - gv;
  const float sh0 = s0a[row], sh1 = s1a[row], sh2 = s2a[row];
  const float gammav = gmv[row];

  const float4* w_prev4 = (const float4*)w_prev;
  const size_t rf4 = (size_t)row * (NN / 4) + lane;  // lane owns n=256b+4lane+c
#pragma unroll
  for (int b = 0; b < 8; ++b) {
    float4 w4 = w_prev4[rf4 + 64 * b];
    v[b].x = ge * v[b].x + om * w4.x;
    v[b].y = ge * v[b].y + om * w4.y;
    v[b].z = ge * v[b].z + om * w4.z;
    v[b].w = ge * v[b].w + om * w4.w;
  }

  // circular conv via 16 shuffles + in-register neighbors (R10-verified)
  float pm[8], np[8];
#pragma unroll
  for (int b = 0; b < 8; ++b) {
    pm[b] = __shfl(v[b].w, lanem1, 64);
    np[b] = __shfl(v[b].x, lanep1, 64);
  }
  float sp = 0.f;
#pragma unroll
  for (int b = 0; b < 8; ++b) {
    const float pv0 = (lane == 0) ? pm[(b + 7) & 7] : pm[b];
    const float nx3 = (lane == 63) ? np[(b + 1) & 7] : np[b];
    const float w0 = v[b].x, w1 = v[b].y, w2 = v[b].z, w3 = v[b].w;
    float t0 = sh0 * pv0 + sh1 * w0 + sh2 * w1;
    float t1 = sh0 * w0 + sh1 * w1 + sh2 * w2;
    float t2 = sh0 * w1 + sh1 * w2 + sh2 * w3;
    float t3 = sh0 * w2 + sh1 * w3 + sh2 * nx3;
    float p0 = __expf(gammav * __logf(t0));  // wt^gamma ; wt>0
    float p1 = __expf(gammav * __logf(t1));
    float p2 = __expf(gammav * __logf(t2));
    float p3 = __expf(gammav * __logf(t3));
    v[b].x = p0;
    v[b].y = p1;
    v[b].z = p2;
    v[b].w = p3;
    sp += (p0 + p1) + (p2 + p3);
  }
  const float spt = wave_sum(sp);
  const float pinv = 1.0f / (spt + EPSF);

  float4* out4 = (float4*)out;
#pragma unroll
  for (int b = 0; b < 8; ++b) {
    float4 o;
    o.x = v[b].x * pinv;
    o.y = v[b].y * pinv;
    o.z = v[b].z * pinv;
    o.w = v[b].w * pinv;
    out4[rf4 + 64 * b] = o;
  }
}

// ---------------- fallback (round-4 monolith, no workspace) ----------------
__global__ __launch_bounds__(1024) void ntm_main_fallback(
    const float* __restrict__ kptr, const float* __restrict__ beta_,
    const float* __restrict__ g_, const float* __restrict__ s_,
    const float* __restrict__ gamma_, const float* __restrict__ w_prev,
    const float* __restrict__ Mptr, float* __restrict__ out) {
  __shared__ float red[16][16];
  __shared__ float edges[16][16][2];
  const int t = threadIdx.x;
  const int lane = t & 63;
  const int w = __builtin_amdgcn_readfirstlane(t >> 6);
  const int l15 = lane & 15;
  const int lg = lane >> 4;
  const int b0 = blockIdx.x * 16;

  const float* kr = kptr + (b0 + l15) * CC + lg * 8;
  bf16x8 ah[4], al[4];
  float ksq = 0.f;
#pragma unroll
  for (int ks = 0; ks < 4; ++ks) {
    float4 a0 = *(const float4*)(kr + ks * 32);
    float4 a1 = *(const float4*)(kr + ks * 32 + 4);
    split8(a0, a1, ah[ks], al[ks], ksq);
  }
  ksq += __shfl_xor(ksq, 16, 64);
  ksq += __shfl_xor(ksq, 32, 64);
  const float ikn_own = 1.0f / sqrtf(ksq);

  f32x4 accT[8];
  float imn[8];
#pragma unroll
  for (int tt = 0; tt < 8; ++tt) {
    const int n0t = 128 * w + 16 * tt;
    const float* mr = Mptr + (size_t)(n0t + l15) * CC + lg * 8;
    f32x4 acc = {0.f, 0.f, 0.f, 0.f};
    float msq = 0.f;
#pragma unroll
    for (int ks = 0; ks < 4; ++ks) {
      float4 m0 = *(const float4*)(mr + ks * 32);
      float4 m1 = *(const float4*)(mr + ks * 32 + 4);
      bf16x8 bh, bl;
      split8(m0, m1, bh, bl, msq);
      acc = __builtin_amdgcn_mfma_f32_16x16x32_bf16(ah[ks], bh, acc, 0, 0, 0);
      acc = __builtin_amdgcn_mfma_f32_16x16x32_bf16(al[ks], bh, acc, 0, 0, 0);
      acc = __builtin_amdgcn_mfma_f32_16x16x32_bf16(ah[ks], bl, acc, 0, 0, 0);
    }
    msq += __shfl_xor(msq, 16, 64);
    msq += __shfl_xor(msq, 32, 64);
    imn[tt] = 1.0f / sqrtf(msq);
    accT[tt] = acc;
  }

#pragma unroll
  for (int q = 0; q < 4; ++q) {
    const int rr = lg * 4 + q;
    const float zb = softplusf(beta_[b0 + rr]) * __shfl(ikn_own, rr, 64);
    float rs = 0.f;
#pragma unroll
    for (int tt = 0; tt < 8; ++tt) {
      float e = __expf(accT[tt][q] * imn[tt] * zb);
      accT[tt][q] = e;
      rs += e;
    }
    rs += __shfl_xor(rs, 1, 64);
    rs += __shfl_xor(rs, 2, 64);
    rs += __shfl_xor(rs, 4, 64);
    rs += __shfl_xor(rs, 8, 64);
    if (l15 == 0) red[rr][w] = rs;
  }
  __syncthreads();

#pragma unroll
  for (int q = 0; q < 4; ++q) {
    const int rr = lg * 4 + q;
    float4 p0 = *(const float4*)&red[rr][0];
    float4 p1 = *(const float4*)&red[rr][4];
    float4 p2 = *(const float4*)&red[rr][8];
    float4 p3 = *(const float4*)&red[rr][12];
    float tot = (p0.x + p0.y + p0.z + p0.w) + (p1.x + p1.y + p1.z + p1.w) +
                (p2.x + p2.y + p2.z + p2.w) + (p3.x + p3.y + p3.z + p3.w);
    const float gv = 1.0f / (1.0f + __expf(-g_[b0 + rr]));
    const float ge = gv / tot;
    const float om = 1.0f - gv;
    const size_t rbase = (size_t)(b0 + rr) * NN + 128 * w + l15;
#pragma unroll
    for (int tt = 0; tt < 8; ++tt) {
      float wpv = w_prev[rbase + 16 * tt];
      accT[tt][q] = ge * accT[tt][q] + om * wpv;
    }
    if (l15 == 0) edges[rr][w][0] = accT[0][q];
    if (l15 == 15) edges[rr][w][1] = accT[7][q];
  }
  __syncthreads();

  const int tm = (lane & 48) | ((lane + 15) & 15);
  const int tp = (lane & 48) | ((lane + 1) & 15);
#pragma unroll
  for (int q = 0; q < 4; ++q) {
    const int rr = lg * 4 + q;
    float sh0 = s_[3 * (b0 + rr)];
    float sh1 = s_[3 * (b0 + rr) + 1];
    float sh2 = s_[3 * (b0 + rr) + 2];
    float shm = fmaxf(sh0, fmaxf(sh1, sh2));
    float e0 = __expf(sh0 - shm), e1 = __expf(sh1 - shm), e2 = __expf(sh2 - shm);
    float sden = 1.0f / (e0 + e1 + e2);
    sh0 = e0 * sden; sh1 = e1 * sden; sh2 = e2 * sden;
    const float gammav = 1.0f + softplusf(gamma_[b0 + rr]);
    const float eL = edges[rr][(w + 15) & 15][1];
    const float eR = edges[rr][(w + 1) & 15][0];
    float sm[8], sp[8];
#pragma unroll
    for (int tt = 0; tt < 8; ++tt) {
      sm[tt] = __shfl(accT[tt][q], tm, 64);
      sp[tt] = __shfl(accT[tt][q], tp, 64);
    }
    float rs = 0.f;
#pragma unroll
    for (int tt = 0; tt < 8; ++tt) {
      float pv = (l15 == 0) ? ((tt == 0) ? eL : sm[tt - 1]) : sm[tt];
      float nx = (l15 == 15) ? ((tt == 7) ? eR : sp[tt + 1]) : sp[tt];
      float wt = sh0 * pv + sh1 * accT[tt][q] + sh2 * nx;
      float p = __expf(gammav * __logf(wt));
      accT[tt][q] = p;
      rs += p;
    }
    rs += __shfl_xor(rs, 1, 64);
    rs += __shfl_xor(rs, 2, 64);
    rs += __shfl_xor(rs, 4, 64);
    rs += __shfl_xor(rs, 8, 64);
    if (l15 == 0) red[rr][w] = rs;
  }
  __syncthreads();

#pragma unroll
  for (int q = 0; q < 4; ++q) {
    const int rr = lg * 4 + q;
    float4 p0 = *(const float4*)&red[rr][0];
    float4 p1 = *(const float4*)&red[rr][4];
    float4 p2 = *(const float4*)&red[rr][8];
    float4 p3 = *(const float4*)&red[rr][12];
    float tot = (p0.x + p0.y + p0.z + p0.w) + (p1.x + p1.y + p1.z + p1.w) +
                (p2.x + p2.y + p2.z + p2.w) + (p3.x + p3.y + p3.z + p3.w);
    const float pinv = 1.0f / (tot + EPSF);
    const size_t rbase = (size_t)(b0 + rr) * NN + 128 * w + l15;
#pragma unroll
    for (int tt = 0; tt < 8; ++tt) {
      out[rbase + 16 * tt] = accT[tt][q] * pinv;
    }
  }
}

extern "C" void kernel_launch(void* const* d_in, const int* in_sizes, int n_in,
                              void* d_out, int out_size, void* d_ws, size_t ws_size,
                              hipStream_t stream) {
  const float* k = (const float*)d_in[0];
  const float* beta = (const float*)d_in[1];
  const float* g = (const float*)d_in[2];
  const float* s = (const float*)d_in[3];
  const float* gamma = (const float*)d_in[4];
  const float* w_prev = (const float*)d_in[5];
  const float* M = (const float*)d_in[6];
  float* out = (float*)d_out;

  // workspace layout (bytes)
  char* ws = (char*)d_ws;
  bf16x8* Mhf = (bf16x8*)(ws + 0);        // 512 KB (128 grp * 4 ks * 64 ln)
  bf16x8* Mlf = (bf16x8*)(ws + 524288);   // 512 KB
  bf16x8* Khf = (bf16x8*)(ws + 1048576);  // 1 MB (256 grp)
  bf16x8* Klf = (bf16x8*)(ws + 2097152);  // 1 MB
  float* imn = (float*)(ws + 3145728);    // 2048
  float* zb = imn + 2048;                 // 4096
  float* gvv = zb + 4096;
  float* gmv = gvv + 4096;
  float* s0a = gmv + 4096;
  float* s1a = s0a + 4096;
  float* s2a = s1a + 4096;
  const size_t need = 3145728 + 2048 * 4 + 6 * 4096 * 4;

  if (ws_size >= need) {
    ntm_prep_kernel<<<112, 256, 0, stream>>>(k, beta, g, s, gamma, M, Mhf, Mlf,
                                             Khf, Klf, imn, zb, gvv, gmv, s0a,
                                             s1a, s2a);
    ntm_main_kernel<<<256, 1024, 0, stream>>>(w_prev, Mhf, Mlf, Khf, Klf, imn,
                                              zb, gvv, gmv, s0a, s1a, s2a, out);
  } else {
    ntm_main_fallback<<<256, 1024, 0, stream>>>(k, beta, g, s, gamma, w_prev,
                                                M, out);
  }
}